// Round 10
// baseline (355.743 us; speedup 1.0000x reference)
//
#include <hip/hip_runtime.h>
#include <hip/hip_bf16.h>

typedef __attribute__((ext_vector_type(8))) short short8;
typedef __attribute__((ext_vector_type(4))) short short4v;
typedef __attribute__((ext_vector_type(4))) float f32x4;

#define INV_TEMP 0.044194173824159216f

__device__ __forceinline__ ushort f2bf(float f) {
  unsigned u = __float_as_uint(f);
  unsigned r = (u + 0x7FFFu + ((u >> 16) & 1u)) >> 16;   // RNE
  return (ushort)r;
}
__device__ __forceinline__ float bf2f(ushort u) {
  union { unsigned i; float f; } x; x.i = ((unsigned)u) << 16; return x.f;
}

// async global->LDS, 16B per lane. LDS dest = wave-uniform base + lane*16;
// global source is per-lane (carries the inverse swizzle).
__device__ __forceinline__ void gload_lds16(const void* g, void* l) {
  __builtin_amdgcn_global_load_lds(
      (const __attribute__((address_space(1))) unsigned int*)(unsigned long long)(uintptr_t)g,
      (__attribute__((address_space(3))) unsigned int*)(unsigned)(uintptr_t)l,
      16, 0, 0);
}

// ---------------- all weight transposes in one launch ----------------
__global__ __launch_bounds__(256)
void transpose_cvt_all(const float* __restrict__ Wq, const float* __restrict__ Wk,
                       const float* __restrict__ Wv, const float* __restrict__ W1,
                       const float* __restrict__ W2,
                       ushort* __restrict__ Tq, ushort* __restrict__ Tk,
                       ushort* __restrict__ Tv, ushort* __restrict__ T1,
                       ushort* __restrict__ T2) {
  const int z = blockIdx.z;
  const int K = (z < 3) ? 1024 : 512;
  const int N = (z == 4) ? 1024 : 512;
  if (blockIdx.x * 32 >= N || blockIdx.y * 32 >= K) return;
  const float* W = z == 0 ? Wq : (z == 1 ? Wk : (z == 2 ? Wv : (z == 3 ? W1 : W2)));
  ushort* WT = z == 0 ? Tq : (z == 1 ? Tk : (z == 2 ? Tv : (z == 3 ? T1 : T2)));
  __shared__ float tile[32][33];
  const int n0 = blockIdx.x * 32, k0 = blockIdx.y * 32;
  const int tx = threadIdx.x & 31, ty = threadIdx.x >> 5;
  #pragma unroll
  for (int i = ty; i < 32; i += 8)
    tile[i][tx] = W[(long)(k0 + i) * N + n0 + tx];
  __syncthreads();
  #pragma unroll
  for (int i = ty; i < 32; i += 8)
    WT[(long)(n0 + i) * K + k0 + tx] = f2bf(tile[tx][i]);
}

// ---------------- bf16 transpose per batch: in (S,D) -> out (D,S) ----------------
__global__ __launch_bounds__(256)
void transpose_bf16(const ushort* __restrict__ in, ushort* __restrict__ out, int S, int D) {
  __shared__ ushort tile[32][33];
  const ushort* inb = in + (long)blockIdx.z * S * D;
  ushort* outb = out + (long)blockIdx.z * S * D;
  const int d0 = blockIdx.x * 32, s0 = blockIdx.y * 32;
  const int tx = threadIdx.x & 31, ty = threadIdx.x >> 5;
  #pragma unroll
  for (int i = ty; i < 32; i += 8)
    tile[i][tx] = inb[(long)(s0 + i) * D + d0 + tx];
  __syncthreads();
  #pragma unroll
  for (int i = ty; i < 32; i += 8)
    outb[(long)(d0 + i) * S + s0 + tx] = tile[tx][i];
}

// ---------------- merged LayerNorm over D=512: q from f32, k/v from bf16 ----------------
__global__ __launch_bounds__(256)
void ln3_kernel(const float* __restrict__ Xq, const ushort* __restrict__ Xk,
                const ushort* __restrict__ Xv,
                const float* __restrict__ gq, const float* __restrict__ beq,
                const float* __restrict__ gk, const float* __restrict__ bek,
                const float* __restrict__ gv, const float* __restrict__ bev,
                ushort* __restrict__ Oq, ushort* __restrict__ Ok, ushort* __restrict__ Ov) {
  const int which = blockIdx.y;
  const float* g = which == 0 ? gq : (which == 1 ? gk : gv);
  const float* be = which == 0 ? beq : (which == 1 ? bek : bev);
  ushort* out = which == 0 ? Oq : (which == 1 ? Ok : Ov);
  const float scale = which == 0 ? INV_TEMP : 1.0f;

  const int row = blockIdx.x * 4 + (threadIdx.x >> 6);
  const int lane = threadIdx.x & 63;
  f32x4 v0, v1;
  if (which == 0) {
    const float* x = Xq + (long)row * 512 + lane * 8;
    v0 = *(const f32x4*)x;
    v1 = *(const f32x4*)(x + 4);
  } else {
    const ushort* x = (which == 1 ? Xk : Xv) + (long)row * 512 + lane * 8;
    short8 vv = *(const short8*)x;
    #pragma unroll
    for (int j = 0; j < 4; j++) { v0[j] = bf2f((ushort)vv[j]); v1[j] = bf2f((ushort)vv[4 + j]); }
  }
  float s = v0[0]+v0[1]+v0[2]+v0[3]+v1[0]+v1[1]+v1[2]+v1[3];
  float ss = v0[0]*v0[0]+v0[1]*v0[1]+v0[2]*v0[2]+v0[3]*v0[3]
           + v1[0]*v1[0]+v1[1]*v1[1]+v1[2]*v1[2]+v1[3]*v1[3];
  #pragma unroll
  for (int off = 32; off; off >>= 1) { s += __shfl_xor(s, off); ss += __shfl_xor(ss, off); }
  const float mean = s * (1.0f/512.0f);
  const float var  = ss * (1.0f/512.0f) - mean*mean;
  const float rs = rsqrtf(var + 1e-6f);
  f32x4 g0 = *(const f32x4*)(g + lane*8);
  f32x4 g1 = *(const f32x4*)(g + lane*8 + 4);
  f32x4 b0 = *(const f32x4*)(be + lane*8);
  f32x4 b1 = *(const f32x4*)(be + lane*8 + 4);
  union { short8 v; ushort u[8]; } o;
  #pragma unroll
  for (int j = 0; j < 4; j++) o.u[j]     = f2bf(((v0[j]-mean)*rs*g0[j] + b0[j]) * scale);
  #pragma unroll
  for (int j = 0; j < 4; j++) o.u[4 + j] = f2bf(((v1[j]-mean)*rs*g1[j] + b1[j]) * scale);
  *(short8*)(out + (long)row * 512 + lane * 8) = o.v;
}

// ---------------- scores kernel: 256x256 tile, BM=BN=256, BK=64, K=512 ----------------
// 512 threads / 8 waves (2M x 4N), per-wave 128x64 = acc[8][4]; double-buffered
// LDS (128KB), 2-tile-ahead staging, counted vmcnt; epilogue = 4x 64-row
// transpose-pane passes: masked exp -> bf16 attn + per-row partial sums.
// partial layout: [8 batches][8 bx][2048 rows].
__global__ __launch_bounds__(512)
void gemm_scores256(const ushort* __restrict__ qn, const ushort* __restrict__ kn,
                    const int* __restrict__ maskp, ushort* __restrict__ Cb,
                    float* __restrict__ partial) {
  __shared__ char smem_raw[131072];
  ushort (*As)[16384] = (ushort(*)[16384])smem_raw;            // 2 x 32KB
  ushort (*Bs)[16384] = (ushort(*)[16384])(smem_raw + 65536);  // 2 x 32KB
  float* smf = (float*)smem_raw;                               // [64][260] pane (67KB)

  const int tid = threadIdx.x;
  const int lane = tid & 63;
  const int wave = tid >> 6;       // 0..7
  const int wr = wave >> 2;        // 0..1  (128-row slab)
  const int wc = wave & 3;         // 0..3  (64-col slab)

  // XCD-aware bijective chunk swizzle (nwg = 512, divisible by 8)
  int lin = blockIdx.x + 8 * (blockIdx.y + 8 * blockIdx.z);
  const int q8 = 64;               // 512/8
  const int swz = (lin & 7) * q8 + (lin >> 3);
  const int bx = swz & 7;
  const int by = (swz >> 3) & 7;
  const int bz = swz >> 6;

  const long zb = bz;
  const ushort* Ab = qn + zb * (2048L * 512) + (long)by * 256 * 512;
  const ushort* Bb = kn + zb * (2048L * 512) + (long)bx * 256 * 512;
  const int nt = 8;                // K=512 / BK=64

  // staging: 2048 granules of 16B per 32KB tile -> 4 per thread per operand
  auto stage = [&](int buf, int t) {
    const long kt = (long)t << 6;
    #pragma unroll
    for (int i = 0; i < 4; i++) {
      const int c = i * 512 + tid;          // 0..2047
      const int row = c >> 3, g = c & 7, gsrc = g ^ (row & 7);
      gload_lds16(Ab + (long)row * 512 + kt + gsrc * 8, (char*)As[buf] + c * 16);
      gload_lds16(Bb + (long)row * 512 + kt + gsrc * 8, (char*)Bs[buf] + c * 16);
    }
  };

  f32x4 acc[8][4];
  #pragma unroll
  for (int m = 0; m < 8; m++)
    #pragma unroll
    for (int n = 0; n < 4; n++)
      acc[m][n] = f32x4{0.f, 0.f, 0.f, 0.f};

  stage(0, 0);
  stage(1, 1);

  for (int t = 0; t < nt; ++t) {
    const int buf = t & 1;
    if (t == nt - 1) {
      asm volatile("s_waitcnt vmcnt(0)" ::: "memory");
    } else {
      asm volatile("s_waitcnt vmcnt(8)" ::: "memory");
    }
    __builtin_amdgcn_s_barrier();
    __builtin_amdgcn_sched_barrier(0);

    #pragma unroll
    for (int ks = 0; ks < 2; ks++) {
      short8 af[8], bfr[4];
      const int kb = ks * 64 + ((lane >> 4) << 4);
      #pragma unroll
      for (int m = 0; m < 8; m++) {
        const int row = wr * 128 + m * 16 + (lane & 15);
        af[m] = *(const short8*)((const char*)As[buf] +
                 ((row << 7) | (kb ^ ((row & 7) << 4))));
      }
      #pragma unroll
      for (int n = 0; n < 4; n++) {
        const int col = wc * 64 + n * 16 + (lane & 15);
        bfr[n] = *(const short8*)((const char*)Bs[buf] +
                  ((col << 7) | (kb ^ ((col & 7) << 4))));
      }
      __builtin_amdgcn_s_setprio(1);
      #pragma unroll
      for (int m = 0; m < 8; m++)
        #pragma unroll
        for (int n = 0; n < 4; n++)
          acc[m][n] = __builtin_amdgcn_mfma_f32_16x16x32_bf16(af[m], bfr[n], acc[m][n], 0, 0, 0);
      __builtin_amdgcn_s_setprio(0);
    }
    __builtin_amdgcn_sched_barrier(0);
    __builtin_amdgcn_s_barrier();
    __builtin_amdgcn_sched_barrier(0);
    if (t + 2 < nt) stage(buf, t + 2);
  }

  // epilogue: 4 passes of 64 rows; pane stride 260 f32
  const int c_lane = lane & 15;
  const int r_lane = (lane >> 4) << 2;
  const int r_own = tid >> 3;              // 0..63
  const int cq = (tid & 7) * 32;           // col quarter-of-8
  #pragma unroll
  for (int p = 0; p < 4; p++) {
    const int grow = by * 256 + p * 64 + r_own;
    const int gcol = bx * 256 + cq;
    const int* mrow = maskp + zb * 4194304L + (long)grow * 2048 + gcol;
    int4 mk[8];
    #pragma unroll
    for (int cc = 0; cc < 8; cc++) mk[cc] = *(const int4*)(mrow + cc * 4);

    __syncthreads();                       // pane free (K-loop or prev pass done)
    if (wr == (p >> 1)) {
      const int mbase = (p & 1) * 4;
      #pragma unroll
      for (int mm = 0; mm < 4; mm++)
        #pragma unroll
        for (int n = 0; n < 4; n++)
          #pragma unroll
          for (int r4 = 0; r4 < 4; r4++)
            smf[(mm * 16 + r_lane + r4) * 260 + wc * 64 + n * 16 + c_lane] =
                acc[mbase + mm][n][r4];
    }
    __syncthreads();

    ushort* orow = Cb + zb * 4194304L + (long)grow * 2048 + gcol;
    float rsum = 0.f;
    #pragma unroll
    for (int cc = 0; cc < 4; cc++) {
      f32x4 v0 = *(const f32x4*)&smf[r_own * 260 + cq + cc * 8];
      f32x4 v1 = *(const f32x4*)&smf[r_own * 260 + cq + cc * 8 + 4];
      int4 m0 = mk[cc * 2], m1 = mk[cc * 2 + 1];
      float e0 = m0.x ? __expf(v0[0]) : 0.f;
      float e1 = m0.y ? __expf(v0[1]) : 0.f;
      float e2 = m0.z ? __expf(v0[2]) : 0.f;
      float e3 = m0.w ? __expf(v0[3]) : 0.f;
      float e4 = m1.x ? __expf(v1[0]) : 0.f;
      float e5 = m1.y ? __expf(v1[1]) : 0.f;
      float e6 = m1.z ? __expf(v1[2]) : 0.f;
      float e7 = m1.w ? __expf(v1[3]) : 0.f;
      rsum += (e0 + e1 + e2 + e3) + (e4 + e5 + e6 + e7);
      union { short8 s; ushort u[8]; } o;
      o.u[0] = f2bf(e0); o.u[1] = f2bf(e1); o.u[2] = f2bf(e2); o.u[3] = f2bf(e3);
      o.u[4] = f2bf(e4); o.u[5] = f2bf(e5); o.u[6] = f2bf(e6); o.u[7] = f2bf(e7);
      *(short8*)(orow + cc * 8) = o.s;
    }
    rsum += __shfl_xor(rsum, 1);
    rsum += __shfl_xor(rsum, 2);
    rsum += __shfl_xor(rsum, 4);
    if ((tid & 7) == 0)
      partial[((long)zb * 8 + bx) * 2048 + grow] = rsum;
  }
}

// ---------------- pipelined TN GEMM: C[M,N] = A[M,K] * BT[N,K]^T ----------------
// 256 threads, 4 waves (2M x 2N), per-wave 64x64 output, BK=64, double-buffered
// LDS, 2-tile-ahead async staging, counted vmcnt (never 0 in steady state).
// EPI: 0 none, 1 relu,
//      3 invZ-from-partials row-scale + fused normalized-f32-attn write,
//      4 merged QKV projections (grid z selects A/B/bias/output; A is f32).
template<int EPI, bool HAS_BIAS, bool OUT_BF16, bool A_F32>
__global__ __launch_bounds__(256)
void gemm_tn_pipe(const void* __restrict__ Av, const ushort* __restrict__ Bt,
                  const float* __restrict__ bias,
                  float* __restrict__ Cf, ushort* __restrict__ Cb,
                  float* __restrict__ partial,
                  const float* __restrict__ A2, const float* __restrict__ A3,
                  const ushort* __restrict__ Bt2, const ushort* __restrict__ Bt3,
                  const float* __restrict__ bias2, const float* __restrict__ bias3,
                  ushort* __restrict__ Cb2,
                  int M, int N, int K,
                  long sA, long sB, long sC) {
  __shared__ char smem_raw[66048];
  ushort (*As)[128 * 64] = (ushort(*)[128 * 64])smem_raw;
  ushort (*Bs)[128 * 64] = (ushort(*)[128 * 64])(smem_raw + 32768);
  float* zloc = (float*)(smem_raw + 65536);

  const int tid = threadIdx.x;
  const int lane = tid & 63;
  const int wave = tid >> 6;       // 0..3
  const int wr = wave >> 1;        // 0..1  (64-row slab)
  const int wc = wave & 1;         // 0..1  (64-col slab)

  // ---- XCD-aware bijective chunk swizzle (T1) ----
  const int gx = gridDim.x, gy = gridDim.y;
  int lin = blockIdx.x + gx * (blockIdx.y + gy * blockIdx.z);
  const int nwg = gx * gy * (int)gridDim.z;
  int swz = lin;
  if ((nwg & 7) == 0) {
    const int q8 = nwg >> 3;
    swz = (lin & 7) * q8 + (lin >> 3);
  }
  const int bx = swz % gx;
  const int tmp = swz / gx;
  const int by = tmp % gy;
  const int bz = tmp / gy;

  const long zb = bz;
  const float* Afp;
  const ushort* Bb;
  const float* bias_p = bias;
  if constexpr (EPI == 4) {
    Afp = (bz == 0 ? (const float*)Av : (bz == 1 ? A2 : A3)) + (long)by * 128 * K;
    Bb = (bz == 0 ? Bt : (bz == 1 ? Bt2 : Bt3)) + (long)bx * 128 * K;
    bias_p = bz == 0 ? bias : (bz == 1 ? bias2 : bias3);
  } else {
    Afp = (const float*)Av + zb * sA + (long)by * 128 * K;
    Bb = Bt + zb * sB + (long)bx * 128 * K;
  }
  const ushort* Ab = (const ushort*)Av + zb * sA + (long)by * 128 * K;
  const int rowbase0 = by * 128;
  const int nt = K >> 6;

  if constexpr (EPI == 3) {
    if (tid < 128) {
      float z = 0.f;
      #pragma unroll
      for (int j = 0; j < 8; j++)
        z += partial[((long)(zb * 8 + j)) * 2048 + rowbase0 + tid];
      zloc[tid] = 1.0f / z;
    }
  }

  // stage K-tile t into buffer buf.
  auto stage = [&](int buf, int t) {
    const long kt = (long)t << 6;
    if constexpr (A_F32) {
      f32x4 a[4][2];
      #pragma unroll
      for (int i = 0; i < 4; i++) {
        const int c = i * 256 + tid;
        const int row = c >> 3, g = c & 7;
        const float* p = Afp + (long)row * K + kt + g * 8;
        a[i][0] = *(const f32x4*)p;
        a[i][1] = *(const f32x4*)(p + 4);
      }
      #pragma unroll
      for (int i = 0; i < 4; i++) {
        const int c = i * 256 + tid;
        const int row = c >> 3, g = c & 7, gsrc = g ^ (row & 7);
        gload_lds16(Bb + (long)row * K + kt + gsrc * 8, (char*)Bs[buf] + c * 16);
      }
      #pragma unroll
      for (int i = 0; i < 4; i++) {
        const int c = i * 256 + tid;
        const int row = c >> 3, g = c & 7;
        union { short8 s; ushort u[8]; } o;
        #pragma unroll
        for (int j = 0; j < 4; j++) { o.u[j] = f2bf(a[i][0][j]); o.u[4 + j] = f2bf(a[i][1][j]); }
        *(short8*)((char*)As[buf] + ((row << 7) | ((g << 4) ^ ((row & 7) << 4)))) = o.s;
      }
      asm volatile("s_waitcnt lgkmcnt(0)" ::: "memory");
    } else {
      #pragma unroll
      for (int i = 0; i < 4; i++) {
        const int c = i * 256 + tid;
        const int row = c >> 3, g = c & 7, gsrc = g ^ (row & 7);
        gload_lds16(Ab + (long)row * K + kt + gsrc * 8, (char*)As[buf] + c * 16);
        gload_lds16(Bb + (long)row * K + kt + gsrc * 8, (char*)Bs[buf] + c * 16);
      }
    }
  };

  f32x4 acc[4][4];
  #pragma unroll
  for (int m = 0; m < 4; m++)
    #pragma unroll
    for (int n = 0; n < 4; n++)
      acc[m][n] = f32x4{0.f, 0.f, 0.f, 0.f};

  // prologue: two tiles in flight
  stage(0, 0);
  stage(1, 1);

  for (int t = 0; t < nt; ++t) {
    const int buf = t & 1;
    if (t == nt - 1) {
      asm volatile("s_waitcnt vmcnt(0)" ::: "memory");
    } else if constexpr (A_F32) {
      asm volatile("s_waitcnt vmcnt(4)" ::: "memory");
    } else {
      asm volatile("s_waitcnt vmcnt(8)" ::: "memory");
    }
    __builtin_amdgcn_s_barrier();          // tile-t data visible to all waves
    __builtin_amdgcn_sched_barrier(0);

    // fused normalized-attn f32 write (PV): block bx owns column quarter bx
    if constexpr (EPI == 3) {
      if ((t >> 3) == bx) {
        #pragma unroll
        for (int e = 0; e < 4; e++) {
          const int c = e * 256 + tid;
          const int row = c >> 3, g = c & 7;
          short8 p8 = *(const short8*)((const char*)As[buf] +
                       ((row << 7) | ((g ^ (row & 7)) << 4)));
          const float iz = zloc[row];
          f32x4 o0, o1;
          #pragma unroll
          for (int jj = 0; jj < 4; jj++) {
            o0[jj] = bf2f((ushort)p8[jj]) * iz;
            o1[jj] = bf2f((ushort)p8[4 + jj]) * iz;
          }
          float* dst = Cf + zb * 4194304L + (long)(rowbase0 + row) * 2048 + (t << 6) + g * 8;
          *(f32x4*)dst = o0;
          *(f32x4*)(dst + 4) = o1;
        }
      }
    }

    #pragma unroll
    for (int ks = 0; ks < 2; ks++) {
      short8 af[4], bfr[4];
      const int kb = ks * 64 + ((lane >> 4) << 4);
      #pragma unroll
      for (int m = 0; m < 4; m++) {
        const int row = wr * 64 + m * 16 + (lane & 15);
        af[m] = *(const short8*)((const char*)As[buf] +
                 ((row << 7) | (kb ^ ((row & 7) << 4))));
      }
      #pragma unroll
      for (int n = 0; n < 4; n++) {
        const int col = wc * 64 + n * 16 + (lane & 15);
        bfr[n] = *(const short8*)((const char*)Bs[buf] +
                  ((col << 7) | (kb ^ ((col & 7) << 4))));
      }
      __builtin_amdgcn_s_setprio(1);
      #pragma unroll
      for (int m = 0; m < 4; m++)
        #pragma unroll
        for (int n = 0; n < 4; n++)
          acc[m][n] = __builtin_amdgcn_mfma_f32_16x16x32_bf16(af[m], bfr[n], acc[m][n], 0, 0, 0);
      __builtin_amdgcn_s_setprio(0);
    }
    __builtin_amdgcn_sched_barrier(0);
    __builtin_amdgcn_s_barrier();          // all waves done reading buf
    __builtin_amdgcn_sched_barrier(0);
    if (t + 2 < nt) stage(buf, t + 2);     // overwrite just-read buffer
  }

  // generic epilogue: D[row][col], col = lane&15, row = (lane>>4)*4 + r
  const int c_lane = lane & 15;
  const int r_lane = (lane >> 4) << 2;
  const int colbase = bx * 128 + wc * 64;
  const int rowbase = by * 128 + wr * 64;
  #pragma unroll
  for (int n = 0; n < 4; n++) {
    const int col = colbase + n * 16 + c_lane;
    const float bv = HAS_BIAS ? bias_p[col] : 0.0f;
    #pragma unroll
    for (int m = 0; m < 4; m++) {
      const int rbase = rowbase + m * 16 + r_lane;
      #pragma unroll
      for (int r4 = 0; r4 < 4; r4++) {
        const int row = rbase + r4;
        float vv = acc[m][n][r4] + bv;
        if constexpr (EPI == 1) vv = fmaxf(vv, 0.0f);
        if constexpr (EPI == 3) vv *= zloc[wr * 64 + m * 16 + r_lane + r4];
        const long off = zb * sC + (long)row * N + col;
        if constexpr (EPI == 4) {
          if (bz == 0) Cf[off] = vv;
          else if (bz == 1) Cb[off] = f2bf(vv);
          else Cb2[off] = f2bf(vv);
        } else if constexpr (OUT_BF16) {
          Cb[off] = f2bf(vv);
        } else {
          Cf[off] = vv;
        }
      }
    }
  }
}

extern "C" void kernel_launch(void* const* d_in, const int* in_sizes, int n_in,
                              void* d_out, int out_size, void* d_ws, size_t ws_size,
                              hipStream_t stream) {
  const float* q    = (const float*)d_in[0];
  const float* k    = (const float*)d_in[1];
  const float* v    = (const float*)d_in[2];
  const int*   mask = (const int*)d_in[3];
  const float* Wq   = (const float*)d_in[4];
  const float* bq   = (const float*)d_in[5];
  const float* Wk   = (const float*)d_in[6];
  const float* bk   = (const float*)d_in[7];
  const float* Wv   = (const float*)d_in[8];
  const float* bv   = (const float*)d_in[9];
  const float* g_q  = (const float*)d_in[10];
  const float* be_q = (const float*)d_in[11];
  const float* g_k  = (const float*)d_in[12];
  const float* be_k = (const float*)d_in[13];
  const float* g_v  = (const float*)d_in[14];
  const float* be_v = (const float*)d_in[15];
  const float* W1   = (const float*)d_in[16];
  const float* b1   = (const float*)d_in[17];
  const float* W2   = (const float*)d_in[18];
  const float* b2   = (const float*)d_in[19];

  float* out_mlp  = (float*)d_out;                 // (8,2048,1024)
  float* out_res  = out_mlp + 16777216L;           // (8,2048,1,512)
  float* out_attn = out_res + 8388608L;            // (8,2048,2048)

  char* w = (char*)d_ws;
  ushort* qn      = (ushort*)(w);                   // 16.7MB
  ushort* kn      = (ushort*)(w + 16777216UL);      // 16.7MB
  ushort* kp_bf   = (ushort*)(w + 33554432UL);      // 16.7MB (dead after ln3)
  ushort* vp_bf   = (ushort*)(w + 50331648UL);      // 16.7MB (dead after ln3)
  ushort* attn_bf = (ushort*)(w + 33554432UL);      // 67MB, overlaps kp_bf/vp_bf
  ushort* vn      = (ushort*)(w + 100663296UL);     // 16.7MB
  ushort* vnT     = (ushort*)(w + 117440512UL);     // 16.7MB
  ushort* pv      = (ushort*)(w + 134217728UL);     // 16.7MB
  ushort* h       = (ushort*)(w + 150994944UL);     // 16.7MB
  ushort* wqT     = (ushort*)(w + 167772160UL);     // 1MB (512,1024)
  ushort* wkT     = (ushort*)(w + 168820736UL);
  ushort* wvT     = (ushort*)(w + 169869312UL);
  ushort* w1T     = (ushort*)(w + 170917888UL);     // 0.5MB (512,512)
  ushort* w2T     = (ushort*)(w + 171442176UL);     // 1MB (1024,512)
  float*  partial = (float*)(w + 172490752UL);      // [8][8][2048] f32

  dim3 blk(256);

  // all weight transposes, one launch
  transpose_cvt_all<<<dim3(32, 32, 5), blk, 0, stream>>>(
      Wq, Wk, Wv, W1, W2, wqT, wkT, wvT, w1T, w2T);

  // merged QKV projections: one launch, grid z selects; q->f32, k/v->bf16
  gemm_tn_pipe<4, true, false, true><<<dim3(4, 128, 3), blk, 0, stream>>>(
      q, wqT, bq, out_res, kp_bf, nullptr,
      k, v, wkT, wvT, bk, bv, vp_bf,
      16384, 512, 1024, 0, 0, 0);

  // merged per-token LayerNorms (1/sqrt(DK) folded into qn)
  ln3_kernel<<<dim3(4096, 3), blk, 0, stream>>>(
      out_res, kp_bf, vp_bf, g_q, be_q, g_k, be_k, g_v, be_v, qn, kn, vn);

  // vn -> vnT for PV's B-operand
  transpose_bf16<<<dim3(16, 64, 8), blk, 0, stream>>>(vn, vnT, 2048, 512);

  // scores: 256x256-tile kernel; exp(qn.kn^T) masked -> bf16 + row-sum partials
  gemm_scores256<<<dim3(8, 8, 8), dim3(512), 0, stream>>>(
      qn, kn, mask, attn_bf, partial);

  // PV: invZ computed in-prologue from partials (8 per row); row-scale epilogue +
  // fused normalized f32 attn write (block bx writes column quarter bx)
  gemm_tn_pipe<3, false, true, false><<<dim3(4, 16, 8), blk, 0, stream>>>(
      attn_bf, vnT, nullptr, out_attn, pv, partial,
      nullptr, nullptr, nullptr, nullptr, nullptr, nullptr, nullptr,
      2048, 512, 2048,
      (long)2048 * 2048, (long)512 * 2048, (long)2048 * 512);

  // MLP
  gemm_tn_pipe<1, true, true, false><<<dim3(4, 128, 1), blk, 0, stream>>>(
      pv, w1T, b1, nullptr, h, nullptr,
      nullptr, nullptr, nullptr, nullptr, nullptr, nullptr, nullptr,
      16384, 512, 512, 0, 0, 0);
  gemm_tn_pipe<0, true, false, false><<<dim3(8, 128, 1), blk, 0, stream>>>(
      h, w2T, b2, out_mlp, nullptr, nullptr,
      nullptr, nullptr, nullptr, nullptr, nullptr, nullptr, nullptr,
      16384, 1024, 512, 0, 0, 0);
}

// Round 11
// 341.987 us; speedup vs baseline: 1.0402x; 1.0402x over previous
//
#include <hip/hip_runtime.h>
#include <hip/hip_bf16.h>

typedef __attribute__((ext_vector_type(8))) short short8;
typedef __attribute__((ext_vector_type(4))) short short4v;
typedef __attribute__((ext_vector_type(4))) float f32x4;

#define INV_TEMP 0.044194173824159216f

__device__ __forceinline__ ushort f2bf(float f) {
  unsigned u = __float_as_uint(f);
  unsigned r = (u + 0x7FFFu + ((u >> 16) & 1u)) >> 16;   // RNE
  return (ushort)r;
}
__device__ __forceinline__ float bf2f(ushort u) {
  union { unsigned i; float f; } x; x.i = ((unsigned)u) << 16; return x.f;
}

// async global->LDS, 16B per lane. LDS dest = wave-uniform base + lane*16;
// global source is per-lane (carries the inverse swizzle).
__device__ __forceinline__ void gload_lds16(const void* g, void* l) {
  __builtin_amdgcn_global_load_lds(
      (const __attribute__((address_space(1))) unsigned int*)(unsigned long long)(uintptr_t)g,
      (__attribute__((address_space(3))) unsigned int*)(unsigned)(uintptr_t)l,
      16, 0, 0);
}

// ---------------- all weight transposes in one launch ----------------
__global__ __launch_bounds__(256)
void transpose_cvt_all(const float* __restrict__ Wq, const float* __restrict__ Wk,
                       const float* __restrict__ Wv, const float* __restrict__ W1,
                       const float* __restrict__ W2,
                       ushort* __restrict__ Tq, ushort* __restrict__ Tk,
                       ushort* __restrict__ Tv, ushort* __restrict__ T1,
                       ushort* __restrict__ T2) {
  const int z = blockIdx.z;
  const int K = (z < 3) ? 1024 : 512;
  const int N = (z == 4) ? 1024 : 512;
  if (blockIdx.x * 32 >= N || blockIdx.y * 32 >= K) return;
  const float* W = z == 0 ? Wq : (z == 1 ? Wk : (z == 2 ? Wv : (z == 3 ? W1 : W2)));
  ushort* WT = z == 0 ? Tq : (z == 1 ? Tk : (z == 2 ? Tv : (z == 3 ? T1 : T2)));
  __shared__ float tile[32][33];
  const int n0 = blockIdx.x * 32, k0 = blockIdx.y * 32;
  const int tx = threadIdx.x & 31, ty = threadIdx.x >> 5;
  #pragma unroll
  for (int i = ty; i < 32; i += 8)
    tile[i][tx] = W[(long)(k0 + i) * N + n0 + tx];
  __syncthreads();
  #pragma unroll
  for (int i = ty; i < 32; i += 8)
    WT[(long)(n0 + i) * K + k0 + tx] = f2bf(tile[tx][i]);
}

// ---------------- bf16 transpose per batch: in (S,D) -> out (D,S) ----------------
__global__ __launch_bounds__(256)
void transpose_bf16(const ushort* __restrict__ in, ushort* __restrict__ out, int S, int D) {
  __shared__ ushort tile[32][33];
  const ushort* inb = in + (long)blockIdx.z * S * D;
  ushort* outb = out + (long)blockIdx.z * S * D;
  const int d0 = blockIdx.x * 32, s0 = blockIdx.y * 32;
  const int tx = threadIdx.x & 31, ty = threadIdx.x >> 5;
  #pragma unroll
  for (int i = ty; i < 32; i += 8)
    tile[i][tx] = inb[(long)(s0 + i) * D + d0 + tx];
  __syncthreads();
  #pragma unroll
  for (int i = ty; i < 32; i += 8)
    outb[(long)(d0 + i) * S + s0 + tx] = tile[tx][i];
}

// ---------------- merged LayerNorm over D=512: q from f32, k/v from bf16 ----------------
__global__ __launch_bounds__(256)
void ln3_kernel(const float* __restrict__ Xq, const ushort* __restrict__ Xk,
                const ushort* __restrict__ Xv,
                const float* __restrict__ gq, const float* __restrict__ beq,
                const float* __restrict__ gk, const float* __restrict__ bek,
                const float* __restrict__ gv, const float* __restrict__ bev,
                ushort* __restrict__ Oq, ushort* __restrict__ Ok, ushort* __restrict__ Ov) {
  const int which = blockIdx.y;
  const float* g = which == 0 ? gq : (which == 1 ? gk : gv);
  const float* be = which == 0 ? beq : (which == 1 ? bek : bev);
  ushort* out = which == 0 ? Oq : (which == 1 ? Ok : Ov);
  const float scale = which == 0 ? INV_TEMP : 1.0f;

  const int row = blockIdx.x * 4 + (threadIdx.x >> 6);
  const int lane = threadIdx.x & 63;
  f32x4 v0, v1;
  if (which == 0) {
    const float* x = Xq + (long)row * 512 + lane * 8;
    v0 = *(const f32x4*)x;
    v1 = *(const f32x4*)(x + 4);
  } else {
    const ushort* x = (which == 1 ? Xk : Xv) + (long)row * 512 + lane * 8;
    short8 vv = *(const short8*)x;
    #pragma unroll
    for (int j = 0; j < 4; j++) { v0[j] = bf2f((ushort)vv[j]); v1[j] = bf2f((ushort)vv[4 + j]); }
  }
  float s = v0[0]+v0[1]+v0[2]+v0[3]+v1[0]+v1[1]+v1[2]+v1[3];
  float ss = v0[0]*v0[0]+v0[1]*v0[1]+v0[2]*v0[2]+v0[3]*v0[3]
           + v1[0]*v1[0]+v1[1]*v1[1]+v1[2]*v1[2]+v1[3]*v1[3];
  #pragma unroll
  for (int off = 32; off; off >>= 1) { s += __shfl_xor(s, off); ss += __shfl_xor(ss, off); }
  const float mean = s * (1.0f/512.0f);
  const float var  = ss * (1.0f/512.0f) - mean*mean;
  const float rs = rsqrtf(var + 1e-6f);
  f32x4 g0 = *(const f32x4*)(g + lane*8);
  f32x4 g1 = *(const f32x4*)(g + lane*8 + 4);
  f32x4 b0 = *(const f32x4*)(be + lane*8);
  f32x4 b1 = *(const f32x4*)(be + lane*8 + 4);
  union { short8 v; ushort u[8]; } o;
  #pragma unroll
  for (int j = 0; j < 4; j++) o.u[j]     = f2bf(((v0[j]-mean)*rs*g0[j] + b0[j]) * scale);
  #pragma unroll
  for (int j = 0; j < 4; j++) o.u[4 + j] = f2bf(((v1[j]-mean)*rs*g1[j] + b1[j]) * scale);
  *(short8*)(out + (long)row * 512 + lane * 8) = o.v;
}

// ---------------- dedicated QKV projection GEMM: K=1024, f32 A, 2-deep A-reg pipe ----------------
// 256 threads, 4 waves (2M x 2N), per-wave 64x64, BK=64, nt=16, dbuf LDS.
// A pipeline: loadA(t+2)->regs at bottom of t; writeA(t+1) (cvt+swizzled ds_write)
// at bottom of t consumes regs loaded at bottom of t-1 -> one full iteration of
// HBM-latency cover. B: gload_lds staged 2 tiles ahead, counted vmcnt(12).
// grid (4,128,3): z selects q/k/v; q out f32, k/v out bf16.
__global__ __launch_bounds__(256)
void gemm_proj(const float* __restrict__ Aq, const float* __restrict__ Ak,
               const float* __restrict__ Avv,
               const ushort* __restrict__ Bq, const ushort* __restrict__ Bk,
               const ushort* __restrict__ Bv,
               const float* __restrict__ bq, const float* __restrict__ bk,
               const float* __restrict__ bv,
               float* __restrict__ Oq, ushort* __restrict__ Ok,
               ushort* __restrict__ Ov) {
  constexpr int K = 1024;
  __shared__ char smem_raw[65536];
  ushort (*As)[8192] = (ushort(*)[8192])smem_raw;              // 2 x 16KB
  ushort (*Bs)[8192] = (ushort(*)[8192])(smem_raw + 32768);    // 2 x 16KB

  const int tid = threadIdx.x;
  const int lane = tid & 63;
  const int wave = tid >> 6;
  const int wr = wave >> 1;
  const int wc = wave & 1;

  // T1 swizzle: nwg = 4*128*3 = 1536 (div by 8)
  int lin = blockIdx.x + 4 * (blockIdx.y + 128 * blockIdx.z);
  const int q8 = 192;
  const int swz = (lin & 7) * q8 + (lin >> 3);
  const int bx = swz & 3;
  const int by = (swz >> 2) & 127;
  const int bz = swz >> 9;

  const float* Afp = (bz == 0 ? Aq : (bz == 1 ? Ak : Avv)) + (long)by * 128 * K;
  const ushort* Bb = (bz == 0 ? Bq : (bz == 1 ? Bk : Bv)) + (long)bx * 128 * K;
  const float* bias_p = bz == 0 ? bq : (bz == 1 ? bk : bv);

  auto loadA = [&](int t, f32x4 (&a)[4][2]) {
    const long kt = (long)t << 6;
    #pragma unroll
    for (int i = 0; i < 4; i++) {
      const int c = i * 256 + tid;
      const int row = c >> 3, g = c & 7;
      const float* p = Afp + (long)row * K + kt + g * 8;
      a[i][0] = *(const f32x4*)p;
      a[i][1] = *(const f32x4*)(p + 4);
    }
  };
  auto writeA = [&](int buf, const f32x4 (&a)[4][2]) {
    #pragma unroll
    for (int i = 0; i < 4; i++) {
      const int c = i * 256 + tid;
      const int row = c >> 3, g = c & 7;
      union { short8 s; ushort u[8]; } o;
      #pragma unroll
      for (int j = 0; j < 4; j++) { o.u[j] = f2bf(a[i][0][j]); o.u[4 + j] = f2bf(a[i][1][j]); }
      *(short8*)((char*)As[buf] + ((row << 7) | ((g << 4) ^ ((row & 7) << 4)))) = o.s;
    }
    asm volatile("s_waitcnt lgkmcnt(0)" ::: "memory");
  };
  auto stageB = [&](int buf, int t) {
    const long kt = (long)t << 6;
    #pragma unroll
    for (int i = 0; i < 4; i++) {
      const int c = i * 256 + tid;
      const int row = c >> 3, g = c & 7, gsrc = g ^ (row & 7);
      gload_lds16(Bb + (long)row * K + kt + gsrc * 8, (char*)Bs[buf] + c * 16);
    }
  };

  f32x4 acc[4][4];
  #pragma unroll
  for (int m = 0; m < 4; m++)
    #pragma unroll
    for (int n = 0; n < 4; n++)
      acc[m][n] = f32x4{0.f, 0.f, 0.f, 0.f};

  f32x4 aE[4][2], aO[4][2];

  // prologue (order pinned: B(0) issues before loadA(1) so top-of-0 vmcnt(12)
  // leaves loadA(1)+B(1) [12 newest] in flight while guaranteeing B(0) done)
  loadA(0, aE);
  writeA(0, aE);                 // compiler-inserted wait for aE
  __builtin_amdgcn_sched_barrier(0);
  stageB(0, 0);
  __builtin_amdgcn_sched_barrier(0);
  loadA(1, aO);
  __builtin_amdgcn_sched_barrier(0);
  stageB(1, 1);
  __builtin_amdgcn_sched_barrier(0);

  auto mfma_phase = [&](int buf) {
    #pragma unroll
    for (int ks = 0; ks < 2; ks++) {
      short8 af[4], bfr[4];
      const int kb = ks * 64 + ((lane >> 4) << 4);
      #pragma unroll
      for (int m = 0; m < 4; m++) {
        const int row = wr * 64 + m * 16 + (lane & 15);
        af[m] = *(const short8*)((const char*)As[buf] +
                 ((row << 7) | (kb ^ ((row & 7) << 4))));
      }
      #pragma unroll
      for (int n = 0; n < 4; n++) {
        const int col = wc * 64 + n * 16 + (lane & 15);
        bfr[n] = *(const short8*)((const char*)Bs[buf] +
                  ((col << 7) | (kb ^ ((col & 7) << 4))));
      }
      __builtin_amdgcn_s_setprio(1);
      #pragma unroll
      for (int m = 0; m < 4; m++)
        #pragma unroll
        for (int n = 0; n < 4; n++)
          acc[m][n] = __builtin_amdgcn_mfma_f32_16x16x32_bf16(af[m], bfr[n], acc[m][n], 0, 0, 0);
      __builtin_amdgcn_s_setprio(0);
    }
  };

  #pragma unroll 1
  for (int tt = 0; tt < 8; ++tt) {
    const bool lastp = (tt == 7);
    // ---- even t = 2*tt, buf 0 ----
    asm volatile("s_waitcnt vmcnt(12)" ::: "memory");
    __builtin_amdgcn_s_barrier();
    __builtin_amdgcn_sched_barrier(0);
    mfma_phase(0);
    __builtin_amdgcn_sched_barrier(0);
    __builtin_amdgcn_s_barrier();
    __builtin_amdgcn_sched_barrier(0);
    writeA(1, aO);                             // tile 2tt+1 into buf1
    if (!lastp) { loadA(2 * tt + 2, aE); stageB(0, 2 * tt + 2); }
    __builtin_amdgcn_sched_barrier(0);
    // ---- odd t = 2*tt+1, buf 1 ----
    if (lastp) asm volatile("s_waitcnt vmcnt(0)" ::: "memory");
    else       asm volatile("s_waitcnt vmcnt(12)" ::: "memory");
    __builtin_amdgcn_s_barrier();
    __builtin_amdgcn_sched_barrier(0);
    mfma_phase(1);
    __builtin_amdgcn_sched_barrier(0);
    __builtin_amdgcn_s_barrier();
    __builtin_amdgcn_sched_barrier(0);
    if (!lastp) {
      writeA(0, aE);                           // tile 2tt+2 into buf0
      loadA(2 * tt + 3, aO);
      stageB(1, 2 * tt + 3);
    }
    __builtin_amdgcn_sched_barrier(0);
  }

  // epilogue
  const int c_lane = lane & 15;
  const int r_lane = (lane >> 4) << 2;
  const int colbase = bx * 128 + wc * 64;
  const int rowbase = by * 128 + wr * 64;
  #pragma unroll
  for (int n = 0; n < 4; n++) {
    const int col = colbase + n * 16 + c_lane;
    const float bv2 = bias_p[col];
    #pragma unroll
    for (int m = 0; m < 4; m++) {
      const int rbase = rowbase + m * 16 + r_lane;
      #pragma unroll
      for (int r4 = 0; r4 < 4; r4++) {
        const int row = rbase + r4;
        const float vv = acc[m][n][r4] + bv2;
        const long off = (long)row * 512 + col;
        if (bz == 0)      Oq[off] = vv;
        else if (bz == 1) Ok[off] = f2bf(vv);
        else              Ov[off] = f2bf(vv);
      }
    }
  }
}

// ---------------- scores kernel: 256x256 tile, BM=BN=256, BK=64, K=512 ----------------
__global__ __launch_bounds__(512)
void gemm_scores256(const ushort* __restrict__ qn, const ushort* __restrict__ kn,
                    const int* __restrict__ maskp, ushort* __restrict__ Cb,
                    float* __restrict__ partial) {
  __shared__ char smem_raw[131072];
  ushort (*As)[16384] = (ushort(*)[16384])smem_raw;            // 2 x 32KB
  ushort (*Bs)[16384] = (ushort(*)[16384])(smem_raw + 65536);  // 2 x 32KB
  float* smf = (float*)smem_raw;                               // [64][260] pane

  const int tid = threadIdx.x;
  const int lane = tid & 63;
  const int wave = tid >> 6;       // 0..7
  const int wr = wave >> 2;        // 0..1  (128-row slab)
  const int wc = wave & 3;         // 0..3  (64-col slab)

  int lin = blockIdx.x + 8 * (blockIdx.y + 8 * blockIdx.z);
  const int q8 = 64;               // 512/8
  const int swz = (lin & 7) * q8 + (lin >> 3);
  const int bx = swz & 7;
  const int by = (swz >> 3) & 7;
  const int bz = swz >> 6;

  const long zb = bz;
  const ushort* Ab = qn + zb * (2048L * 512) + (long)by * 256 * 512;
  const ushort* Bb = kn + zb * (2048L * 512) + (long)bx * 256 * 512;
  const int nt = 8;

  auto stage = [&](int buf, int t) {
    const long kt = (long)t << 6;
    #pragma unroll
    for (int i = 0; i < 4; i++) {
      const int c = i * 512 + tid;
      const int row = c >> 3, g = c & 7, gsrc = g ^ (row & 7);
      gload_lds16(Ab + (long)row * 512 + kt + gsrc * 8, (char*)As[buf] + c * 16);
      gload_lds16(Bb + (long)row * 512 + kt + gsrc * 8, (char*)Bs[buf] + c * 16);
    }
  };

  f32x4 acc[8][4];
  #pragma unroll
  for (int m = 0; m < 8; m++)
    #pragma unroll
    for (int n = 0; n < 4; n++)
      acc[m][n] = f32x4{0.f, 0.f, 0.f, 0.f};

  stage(0, 0);
  stage(1, 1);

  for (int t = 0; t < nt; ++t) {
    const int buf = t & 1;
    if (t == nt - 1) {
      asm volatile("s_waitcnt vmcnt(0)" ::: "memory");
    } else {
      asm volatile("s_waitcnt vmcnt(8)" ::: "memory");
    }
    __builtin_amdgcn_s_barrier();
    __builtin_amdgcn_sched_barrier(0);

    #pragma unroll
    for (int ks = 0; ks < 2; ks++) {
      short8 af[8], bfr[4];
      const int kb = ks * 64 + ((lane >> 4) << 4);
      #pragma unroll
      for (int m = 0; m < 8; m++) {
        const int row = wr * 128 + m * 16 + (lane & 15);
        af[m] = *(const short8*)((const char*)As[buf] +
                 ((row << 7) | (kb ^ ((row & 7) << 4))));
      }
      #pragma unroll
      for (int n = 0; n < 4; n++) {
        const int col = wc * 64 + n * 16 + (lane & 15);
        bfr[n] = *(const short8*)((const char*)Bs[buf] +
                  ((col << 7) | (kb ^ ((col & 7) << 4))));
      }
      __builtin_amdgcn_s_setprio(1);
      #pragma unroll
      for (int m = 0; m < 8; m++)
        #pragma unroll
        for (int n = 0; n < 4; n++)
          acc[m][n] = __builtin_amdgcn_mfma_f32_16x16x32_bf16(af[m], bfr[n], acc[m][n], 0, 0, 0);
      __builtin_amdgcn_s_setprio(0);
    }
    __builtin_amdgcn_sched_barrier(0);
    __builtin_amdgcn_s_barrier();
    __builtin_amdgcn_sched_barrier(0);
    if (t + 2 < nt) stage(buf, t + 2);
  }

  // epilogue: 4 passes of 64 rows; pane stride 260 f32
  const int c_lane = lane & 15;
  const int r_lane = (lane >> 4) << 2;
  const int r_own = tid >> 3;
  const int cq = (tid & 7) * 32;
  #pragma unroll
  for (int p = 0; p < 4; p++) {
    const int grow = by * 256 + p * 64 + r_own;
    const int gcol = bx * 256 + cq;
    const int* mrow = maskp + zb * 4194304L + (long)grow * 2048 + gcol;
    int4 mk[8];
    #pragma unroll
    for (int cc = 0; cc < 8; cc++) mk[cc] = *(const int4*)(mrow + cc * 4);

    __syncthreads();
    if (wr == (p >> 1)) {
      const int mbase = (p & 1) * 4;
      #pragma unroll
      for (int mm = 0; mm < 4; mm++)
        #pragma unroll
        for (int n = 0; n < 4; n++)
          #pragma unroll
          for (int r4 = 0; r4 < 4; r4++)
            smf[(mm * 16 + r_lane + r4) * 260 + wc * 64 + n * 16 + c_lane] =
                acc[mbase + mm][n][r4];
    }
    __syncthreads();

    ushort* orow = Cb + zb * 4194304L + (long)grow * 2048 + gcol;
    float rsum = 0.f;
    #pragma unroll
    for (int cc = 0; cc < 4; cc++) {
      f32x4 v0 = *(const f32x4*)&smf[r_own * 260 + cq + cc * 8];
      f32x4 v1 = *(const f32x4*)&smf[r_own * 260 + cq + cc * 8 + 4];
      int4 m0 = mk[cc * 2], m1 = mk[cc * 2 + 1];
      float e0 = m0.x ? __expf(v0[0]) : 0.f;
      float e1 = m0.y ? __expf(v0[1]) : 0.f;
      float e2 = m0.z ? __expf(v0[2]) : 0.f;
      float e3 = m0.w ? __expf(v0[3]) : 0.f;
      float e4 = m1.x ? __expf(v1[0]) : 0.f;
      float e5 = m1.y ? __expf(v1[1]) : 0.f;
      float e6 = m1.z ? __expf(v1[2]) : 0.f;
      float e7 = m1.w ? __expf(v1[3]) : 0.f;
      rsum += (e0 + e1 + e2 + e3) + (e4 + e5 + e6 + e7);
      union { short8 s; ushort u[8]; } o;
      o.u[0] = f2bf(e0); o.u[1] = f2bf(e1); o.u[2] = f2bf(e2); o.u[3] = f2bf(e3);
      o.u[4] = f2bf(e4); o.u[5] = f2bf(e5); o.u[6] = f2bf(e6); o.u[7] = f2bf(e7);
      *(short8*)(orow + cc * 8) = o.s;
    }
    rsum += __shfl_xor(rsum, 1);
    rsum += __shfl_xor(rsum, 2);
    rsum += __shfl_xor(rsum, 4);
    if ((tid & 7) == 0)
      partial[((long)zb * 8 + bx) * 2048 + grow] = rsum;
  }
}

// ---------------- pipelined TN GEMM (bf16 A): C = A * BT^T ----------------
// EPI: 0 none, 1 relu, 3 invZ row-scale + fused normalized-f32-attn write.
template<int EPI, bool HAS_BIAS, bool OUT_BF16>
__global__ __launch_bounds__(256)
void gemm_tn_pipe(const ushort* __restrict__ Ain, const ushort* __restrict__ Bt,
                  const float* __restrict__ bias,
                  float* __restrict__ Cf, ushort* __restrict__ Cb,
                  float* __restrict__ partial,
                  int M, int N, int K,
                  long sA, long sB, long sC) {
  __shared__ char smem_raw[66048];
  ushort (*As)[128 * 64] = (ushort(*)[128 * 64])smem_raw;
  ushort (*Bs)[128 * 64] = (ushort(*)[128 * 64])(smem_raw + 32768);
  float* zloc = (float*)(smem_raw + 65536);

  const int tid = threadIdx.x;
  const int lane = tid & 63;
  const int wave = tid >> 6;
  const int wr = wave >> 1;
  const int wc = wave & 1;

  const int gx = gridDim.x, gy = gridDim.y;
  int lin = blockIdx.x + gx * (blockIdx.y + gy * blockIdx.z);
  const int nwg = gx * gy * (int)gridDim.z;
  int swz = lin;
  if ((nwg & 7) == 0) {
    const int q8 = nwg >> 3;
    swz = (lin & 7) * q8 + (lin >> 3);
  }
  const int bx = swz % gx;
  const int tmp = swz / gx;
  const int by = tmp % gy;
  const int bz = tmp / gy;

  const long zb = bz;
  const ushort* Ab = Ain + zb * sA + (long)by * 128 * K;
  const ushort* Bb = Bt + zb * sB + (long)bx * 128 * K;
  const int rowbase0 = by * 128;
  const int nt = K >> 6;

  if constexpr (EPI == 3) {
    if (tid < 128) {
      float z = 0.f;
      #pragma unroll
      for (int j = 0; j < 8; j++)
        z += partial[((long)(zb * 8 + j)) * 2048 + rowbase0 + tid];
      zloc[tid] = 1.0f / z;
    }
  }

  auto stage = [&](int buf, int t) {
    const long kt = (long)t << 6;
    #pragma unroll
    for (int i = 0; i < 4; i++) {
      const int c = i * 256 + tid;
      const int row = c >> 3, g = c & 7, gsrc = g ^ (row & 7);
      gload_lds16(Ab + (long)row * K + kt + gsrc * 8, (char*)As[buf] + c * 16);
      gload_lds16(Bb + (long)row * K + kt + gsrc * 8, (char*)Bs[buf] + c * 16);
    }
  };

  f32x4 acc[4][4];
  #pragma unroll
  for (int m = 0; m < 4; m++)
    #pragma unroll
    for (int n = 0; n < 4; n++)
      acc[m][n] = f32x4{0.f, 0.f, 0.f, 0.f};

  stage(0, 0);
  stage(1, 1);

  for (int t = 0; t < nt; ++t) {
    const int buf = t & 1;
    if (t == nt - 1) {
      asm volatile("s_waitcnt vmcnt(0)" ::: "memory");
    } else {
      asm volatile("s_waitcnt vmcnt(8)" ::: "memory");
    }
    __builtin_amdgcn_s_barrier();
    __builtin_amdgcn_sched_barrier(0);

    if constexpr (EPI == 3) {
      if ((t >> 3) == bx) {
        #pragma unroll
        for (int e = 0; e < 4; e++) {
          const int c = e * 256 + tid;
          const int row = c >> 3, g = c & 7;
          short8 p8 = *(const short8*)((const char*)As[buf] +
                       ((row << 7) | ((g ^ (row & 7)) << 4)));
          const float iz = zloc[row];
          f32x4 o0, o1;
          #pragma unroll
          for (int jj = 0; jj < 4; jj++) {
            o0[jj] = bf2f((ushort)p8[jj]) * iz;
            o1[jj] = bf2f((ushort)p8[4 + jj]) * iz;
          }
          float* dst = Cf + zb * 4194304L + (long)(rowbase0 + row) * 2048 + (t << 6) + g * 8;
          *(f32x4*)dst = o0;
          *(f32x4*)(dst + 4) = o1;
        }
      }
    }

    #pragma unroll
    for (int ks = 0; ks < 2; ks++) {
      short8 af[4], bfr[4];
      const int kb = ks * 64 + ((lane >> 4) << 4);
      #pragma unroll
      for (int m = 0; m < 4; m++) {
        const int row = wr * 64 + m * 16 + (lane & 15);
        af[m] = *(const short8*)((const char*)As[buf] +
                 ((row << 7) | (kb ^ ((row & 7) << 4))));
      }
      #pragma unroll
      for (int n = 0; n < 4; n++) {
        const int col = wc * 64 + n * 16 + (lane & 15);
        bfr[n] = *(const short8*)((const char*)Bs[buf] +
                  ((col << 7) | (kb ^ ((col & 7) << 4))));
      }
      __builtin_amdgcn_s_setprio(1);
      #pragma unroll
      for (int m = 0; m < 4; m++)
        #pragma unroll
        for (int n = 0; n < 4; n++)
          acc[m][n] = __builtin_amdgcn_mfma_f32_16x16x32_bf16(af[m], bfr[n], acc[m][n], 0, 0, 0);
      __builtin_amdgcn_s_setprio(0);
    }
    __builtin_amdgcn_sched_barrier(0);
    __builtin_amdgcn_s_barrier();
    __builtin_amdgcn_sched_barrier(0);
    if (t + 2 < nt) stage(buf, t + 2);
  }

  const int c_lane = lane & 15;
  const int r_lane = (lane >> 4) << 2;
  const int colbase = bx * 128 + wc * 64;
  const int rowbase = by * 128 + wr * 64;
  #pragma unroll
  for (int n = 0; n < 4; n++) {
    const int col = colbase + n * 16 + c_lane;
    const float bv = HAS_BIAS ? bias[col] : 0.0f;
    #pragma unroll
    for (int m = 0; m < 4; m++) {
      const int rbase = rowbase + m * 16 + r_lane;
      #pragma unroll
      for (int r4 = 0; r4 < 4; r4++) {
        const int row = rbase + r4;
        float vv = acc[m][n][r4] + bv;
        if constexpr (EPI == 1) vv = fmaxf(vv, 0.0f);
        if constexpr (EPI == 3) vv *= zloc[wr * 64 + m * 16 + r_lane + r4];
        const long off = zb * sC + (long)row * N + col;
        if constexpr (OUT_BF16) Cb[off] = f2bf(vv);
        else                    Cf[off] = vv;
      }
    }
  }
}

extern "C" void kernel_launch(void* const* d_in, const int* in_sizes, int n_in,
                              void* d_out, int out_size, void* d_ws, size_t ws_size,
                              hipStream_t stream) {
  const float* q    = (const float*)d_in[0];
  const float* k    = (const float*)d_in[1];
  const float* v    = (const float*)d_in[2];
  const int*   mask = (const int*)d_in[3];
  const float* Wq   = (const float*)d_in[4];
  const float* bq   = (const float*)d_in[5];
  const float* Wk   = (const float*)d_in[6];
  const float* bk   = (const float*)d_in[7];
  const float* Wv   = (const float*)d_in[8];
  const float* bv   = (const float*)d_in[9];
  const float* g_q  = (const float*)d_in[10];
  const float* be_q = (const float*)d_in[11];
  const float* g_k  = (const float*)d_in[12];
  const float* be_k = (const float*)d_in[13];
  const float* g_v  = (const float*)d_in[14];
  const float* be_v = (const float*)d_in[15];
  const float* W1   = (const float*)d_in[16];
  const float* b1   = (const float*)d_in[17];
  const float* W2   = (const float*)d_in[18];
  const float* b2   = (const float*)d_in[19];

  float* out_mlp  = (float*)d_out;                 // (8,2048,1024)
  float* out_res  = out_mlp + 16777216L;           // (8,2048,1,512)
  float* out_attn = out_res + 8388608L;            // (8,2048,2048)

  char* w = (char*)d_ws;
  ushort* qn      = (ushort*)(w);                   // 16.7MB
  ushort* kn      = (ushort*)(w + 16777216UL);      // 16.7MB
  ushort* kp_bf   = (ushort*)(w + 33554432UL);      // 16.7MB (dead after ln3)
  ushort* vp_bf   = (ushort*)(w + 50331648UL);      // 16.7MB (dead after ln3)
  ushort* attn_bf = (ushort*)(w + 33554432UL);      // 67MB, overlaps kp_bf/vp_bf
  ushort* vn      = (ushort*)(w + 100663296UL);     // 16.7MB
  ushort* vnT     = (ushort*)(w + 117440512UL);     // 16.7MB
  ushort* pv      = (ushort*)(w + 134217728UL);     // 16.7MB
  ushort* h       = (ushort*)(w + 150994944UL);     // 16.7MB
  ushort* wqT     = (ushort*)(w + 167772160UL);     // 1MB (512,1024)
  ushort* wkT     = (ushort*)(w + 168820736UL);
  ushort* wvT     = (ushort*)(w + 169869312UL);
  ushort* w1T     = (ushort*)(w + 170917888UL);     // 0.5MB (512,512)
  ushort* w2T     = (ushort*)(w + 171442176UL);     // 1MB (1024,512)
  float*  partial = (float*)(w + 172490752UL);      // [8][8][2048] f32

  dim3 blk(256);

  // all weight transposes, one launch
  transpose_cvt_all<<<dim3(32, 32, 5), blk, 0, stream>>>(
      Wq, Wk, Wv, W1, W2, wqT, wkT, wvT, w1T, w2T);

  // merged QKV projections: dedicated kernel with 2-deep A-reg pipeline
  gemm_proj<<<dim3(4, 128, 3), blk, 0, stream>>>(
      q, k, v, wqT, wkT, wvT, bq, bk, bv, out_res, kp_bf, vp_bf);

  // merged per-token LayerNorms (1/sqrt(DK) folded into qn)
  ln3_kernel<<<dim3(4096, 3), blk, 0, stream>>>(
      out_res, kp_bf, vp_bf, g_q, be_q, g_k, be_k, g_v, be_v, qn, kn, vn);

  // vn -> vnT for PV's B-operand
  transpose_bf16<<<dim3(16, 64, 8), blk, 0, stream>>>(vn, vnT, 2048, 512);

  // scores: 256x256-tile kernel; exp(qn.kn^T) masked -> bf16 + row-sum partials
  gemm_scores256<<<dim3(8, 8, 8), dim3(512), 0, stream>>>(
      qn, kn, mask, attn_bf, partial);

  // PV: invZ from partials; row-scale epilogue + fused normalized f32 attn write
  gemm_tn_pipe<3, false, true><<<dim3(4, 16, 8), blk, 0, stream>>>(
      attn_bf, vnT, nullptr, out_attn, pv, partial,
      2048, 512, 2048,
      (long)2048 * 2048, (long)512 * 2048, (long)2048 * 512);

  // MLP
  gemm_tn_pipe<1, true, true><<<dim3(4, 128, 1), blk, 0, stream>>>(
      pv, w1T, b1, nullptr, h, nullptr,
      16384, 512, 512, 0, 0, 0);
  gemm_tn_pipe<0, true, false><<<dim3(8, 128, 1), blk, 0, stream>>>(
      h, w2T, b2, out_mlp, nullptr, nullptr,
      16384, 1024, 512, 0, 0, 0);
}